// Round 4
// baseline (375.628 us; speedup 1.0000x reference)
//
#include <hip/hip_runtime.h>
#include <math.h>

// Problem constants
#define Bn    64
#define Cn    3
#define IMG   224
#define PLANE (IMG*IMG)      // 50176
#define C1    6
#define P1    110            // conv1(220) + maxpool2 -> 110
#define NVALID (106*106)     // 11236
#define Hh    32
#define Ww    64
#define UPR   10
#define UPT   10
#define Hg    (Hh*UPR)       // 320
#define Wg    (Ww*UPT)       // 640
#define POOLED_SIZE (Bn*Cn*Hh*Ww)   // 393216
#define NCHUNK 28            // 28 chunks x 4 pooled rows = 112 >= 110
#define NBLK1  (NCHUNK*Bn)   // 1792
#define WSTRIDE 152          // padded 150-float wsum slot
#define ROWB  (IMG*8)        // 1792 B: one NHWC4-f16 input row
#define TPB1  448            // 7 waves: 14 strips / 7 = 2 each

typedef unsigned short u16;
typedef unsigned long long ull;
typedef _Float16 h8v __attribute__((ext_vector_type(8)));   // 8 f16 MFMA frag
typedef float f4v __attribute__((ext_vector_type(4)));      // 16x16 MFMA acc

// workspace layout (floats): wsum[64*152] | counter | pad | wt[128] | x4h(f16)
#define WSUM_FLOATS (Bn*WSTRIDE)               // 9728
#define CTR_OFF     WSUM_FLOATS                // 9728
#define WT_OFF      (WSUM_FLOATS + 4)          // 9732
#define X4H_OFF_F   9864                       // 16B-aligned byte 39456
#define X4B_U16     ((size_t)Bn * PLANE * 4)
#define WS_NEEDED   ((size_t)X4H_OFF_F * 4 + X4B_U16 * 2)
#define MEMSET_BYTES ((CTR_OFF + 1) * 4)

__device__ __forceinline__ unsigned hpack(float a, float b) {
    union { _Float16 h; u16 u; } x, y;
    x.h = (_Float16)a; y.h = (_Float16)b;
    return (unsigned)x.u | ((unsigned)y.u << 16);
}
__device__ __forceinline__ float h2lo(unsigned v) {
    union { _Float16 h; u16 u; } c; c.u = (u16)(v & 0xffffu); return (float)c.h;
}
__device__ __forceinline__ float h2hi(unsigned v) {
    union { _Float16 h; u16 u; } c; c.u = (u16)(v >> 16); return (float)c.h;
}

// group-local broadcast: read lane (group_base + idx) of a 16-lane group
#define GSHFL(v, idx) __shfl((v), (lane & 48) + (idx), 64)

// -------------------------------------------------------------------------
// K1 (MFMA f16, R2 conv structure): fused conv1 + maxpool2 + f16-NHWC4 pack
// + windowed row sums -> atomicAdd into per-image wsum[150]; the LAST block
// (threadfence+counter) computes the whole attention head (ex-K2) for all
// 64 images. 1792 blocks, l = chunk*64 + b -> image b on XCD b%8 (matches
// k3's map; k1's x4h writes land in the L2 k3 gathers from).
// -------------------------------------------------------------------------
__global__ __launch_bounds__(TPB1) void k1_fused(
    const float* __restrict__ x,      // (B,3,224,224)
    const float* __restrict__ w1,     // (6,3,5,5)
    const float* __restrict__ b1,     // (6,)
    const float* __restrict__ w2,     // (16,6,5,5) = (16,150)
    const float* __restrict__ b2,     // (16,)
    const float* __restrict__ fc1w, const float* __restrict__ fc1b,
    const float* __restrict__ fc2w, const float* __restrict__ fc2b,
    float* __restrict__ wsum,         // (64,152) zeroed accumulator
    unsigned* __restrict__ counter,   // zeroed
    float* __restrict__ wt_ws,        // (64,2)
    u16* __restrict__ x4h,            // (B,224,224,4) f16 out
    float* __restrict__ out,
    int do_pack)
{
    __shared__ __attribute__((aligned(16))) unsigned char xs[12 * ROWB + 128];
    __shared__ __attribute__((aligned(16))) _Float16 sa[5][64][8];  // A-frags
    __shared__ float rowR[7][C1][4];
    __shared__ float edgeLo[4][C1][4];
    __shared__ float edgeHi[4][C1][4];
    __shared__ float sfeat[16][16];
    __shared__ float shh[16][8];
    __shared__ unsigned lastFlag;

    const int l     = blockIdx.x;          // 0..1791
    const int b     = l & 63;              // XCD = b%8 (round-robin dispatch)
    const int chunk = l >> 6;              // 0..27
    const int tid   = threadIdx.x;
    const int wid   = tid >> 6;
    const int lane  = tid & 63;
    const int n     = lane & 15;           // B col / A row / C col
    const int g     = lane >> 4;           // K-group (and C row-group)
    const int gy0   = chunk * 8;

    const float* xb = x + (size_t)b * (Cn * PLANE);
    u16* ob = x4h + (size_t)b * PLANE * 4;

    if (wid == 0) {
        // wave 0: build A-frags (weights, k = ic + 4*kx) into LDS
        #pragma unroll
        for (int ky = 0; ky < 5; ++ky) {
            #pragma unroll
            for (int j = 0; j < 8; ++j) {
                const int kmem = g * 8 + j;
                const int ic = kmem & 3, kx = kmem >> 2;
                float w = 0.0f;
                if (n < C1 && ic < 3 && kx < 5)
                    w = w1[((n * 3 + ic) * 5 + ky) * 5 + kx];
                sa[ky][lane][j] = (_Float16)w;
            }
        }
    } else {
        // waves 1-6: stage fp32 NCHW -> f16 NHWC4 LDS (+ x4h pack)
        for (int i = tid - 64; i < 12 * 112; i += TPB1 - 64) {
            const int r = i / 112;
            const int p = i - r * 112;
            const int gy = gy0 + r;
            uint4 U; U.x = U.y = U.z = U.w = 0u;
            if (gy < IMG) {
                const float2 v0 = *(const float2*)(xb + 0 * PLANE + gy * IMG + 2 * p);
                const float2 v1 = *(const float2*)(xb + 1 * PLANE + gy * IMG + 2 * p);
                const float2 v2 = *(const float2*)(xb + 2 * PLANE + gy * IMG + 2 * p);
                U.x = hpack(v0.x, v1.x);
                U.y = hpack(v2.x, 0.0f);
                U.z = hpack(v0.y, v1.y);
                U.w = hpack(v2.y, 0.0f);
            }
            *(uint4*)(xs + r * ROWB + p * 16) = U;
            if (do_pack && r < 8)
                *(uint4*)(ob + ((size_t)gy * IMG + 2 * p) * 4) = U;
        }
    }
    __syncthreads();

    // per-lane A-frags (one b128 each) + bias init
    h8v a[5];
    #pragma unroll
    for (int ky = 0; ky < 5; ++ky) a[ky] = *(const h8v*)&sa[ky][lane][0];
    f4v binit;
    #pragma unroll
    for (int e = 0; e < 4; ++e) {
        const int oc = g * 4 + e;
        binit[e] = (oc < C1) ? b1[oc] : 0.0f;
    }

    float colsum[4][4];
    #pragma unroll
    for (int py = 0; py < 4; ++py)
        #pragma unroll
        for (int e = 0; e < 4; ++e) colsum[py][e] = 0.0f;

    #pragma unroll
    for (int si = 0; si < 2; ++si) {
        const int s = wid * 2 + si;         // strip: conv cols s*16..s*16+15
        const unsigned sByte = (unsigned)(s * 128 + n * 8 + g * 16);

        f4v acc[8];
        #pragma unroll
        for (int q = 0; q < 8; ++q) acc[q] = binit;

        #pragma unroll
        for (int r = 0; r < 12; ++r) {
            h8v bf;
            const unsigned char* bp = xs + r * ROWB + sByte;
            ((ull*)&bf)[0] = *(const ull*)bp;
            ((ull*)&bf)[1] = *(const ull*)(bp + 8);
            #pragma unroll
            for (int ky = 0; ky < 5; ++ky) {
                const int q = r - ky;
                if (q >= 0 && q < 8)
                    acc[q] = __builtin_amdgcn_mfma_f32_16x16x32_f16(
                        a[ky], bf, acc[q], 0, 0, 0);
            }
        }

        // maxpool 2x2 + edge capture + col accumulation
        #pragma unroll
        for (int py = 0; py < 4; ++py) {
            #pragma unroll
            for (int e = 0; e < 4; ++e) {
                float t = fmaxf(acc[2 * py][e], acc[2 * py + 1][e]);
                t = fmaxf(t, __shfl_xor(t, 1, 64));
                if (s == 13 && n >= 12) t = 0.0f;     // junk cols 110,111
                colsum[py][e] += t;
                const int oc = g * 4 + e;
                if (s == 0) {                          // pooled cols 0..3
                    const float c0 = GSHFL(t, 0), c1 = GSHFL(t, 2);
                    const float c2 = GSHFL(t, 4), c3 = GSHFL(t, 6);
                    const float S1 = c0, S2 = S1 + c1, S3 = S2 + c2, S4 = S3 + c3;
                    const float sv = (n == 0) ? S1 : (n == 1) ? S2 : (n == 2) ? S3 : S4;
                    if (n < 4 && oc < C1) edgeLo[py][oc][n] = sv;
                }
                if (s == 13) {                         // pooled cols 106..109
                    const float d109 = GSHFL(t, 10), d108 = GSHFL(t, 8);
                    const float d107 = GSHFL(t, 6),  d106 = GSHFL(t, 4);
                    const float U1 = d109, U2 = U1 + d108, U3 = U2 + d107, U4 = U3 + d106;
                    const float uv = (n == 0) ? U1 : (n == 1) ? U2 : (n == 2) ? U3 : U4;
                    if (n < 4 && oc < C1) edgeHi[py][oc][n] = uv;
                }
            }
        }
    }

    // per-wave row sums
    #pragma unroll
    for (int py = 0; py < 4; ++py) {
        #pragma unroll
        for (int e = 0; e < 4; ++e) {
            float v = colsum[py][e];
            v += __shfl_xor(v, 2, 64);
            v += __shfl_xor(v, 4, 64);
            v += __shfl_xor(v, 8, 64);
            const int oc = g * 4 + e;
            if (n == 0 && oc < C1) rowR[wid][oc][py] = v;
        }
    }
    __syncthreads();

    // slot(oc,ky,kx) -> atomicAdd into per-image wsum (order jitter << tol)
    if (tid < 150) {
        const int oc = tid / 25;
        const int rem = tid - oc * 25;
        const int ky = rem / 5, kx = rem - ky * 5;
        float total = 0.0f;
        #pragma unroll
        for (int py = 0; py < 4; ++py) {
            const int y = chunk * 4 + py;
            const bool valid = (y < P1) && ((unsigned)(y - ky) <= 105u);
            float v = rowR[0][oc][py] + rowR[1][oc][py] + rowR[2][oc][py]
                    + rowR[3][oc][py] + rowR[4][oc][py] + rowR[5][oc][py]
                    + rowR[6][oc][py];
            if (kx > 0) v -= edgeLo[py][oc][kx - 1];
            if (kx < 4) v -= edgeHi[py][oc][3 - kx];
            total += valid ? v : 0.0f;
        }
        atomicAdd(&wsum[b * WSTRIDE + tid], total);
    }

    // ---- last-block head (ex-K2) ----
    __threadfence();
    __syncthreads();
    if (tid == 0) {
        const unsigned old = atomicAdd(counter, 1u);
        lastFlag = (old == (unsigned)(NBLK1 - 1)) ? 1u : 0u;
    }
    __syncthreads();
    if (!lastFlag) return;

    float* hw = (float*)xs;                 // overlay: 16*152 floats = 9728B
    for (int batch = 0; batch < 4; ++batch) {
        const int b0 = batch * 16;
        for (int i = tid; i < 16 * 150; i += TPB1) {
            const int bl = i / 150, j = i - bl * 150;
            hw[bl * WSTRIDE + j] = __hip_atomic_load(
                &wsum[(b0 + bl) * WSTRIDE + j],
                __ATOMIC_ACQUIRE, __HIP_MEMORY_SCOPE_AGENT);
        }
        __syncthreads();
        if (tid < 256) {                    // feat: 16 b x 16 oc
            const int bl = tid >> 4, oc = tid & 15;
            float s = 0.0f;
            for (int j = 0; j < 150; ++j) s += w2[oc * 150 + j] * hw[bl * WSTRIDE + j];
            sfeat[bl][oc] = b2[oc] + s * (1.0f / (float)NVALID);
        }
        __syncthreads();
        if (tid < 128) {                    // fc1+relu: 16 b x 8
            const int bl = tid >> 3, o = tid & 7;
            float s = fc1b[o];
            #pragma unroll
            for (int j = 0; j < 16; ++j) s += fc1w[o * 16 + j] * sfeat[bl][j];
            shh[bl][o] = fmaxf(s, 0.0f);
        }
        __syncthreads();
        if (tid < 32) {                     // fc2+sigmoid*5: 16 b x 2
            const int bl = tid >> 1, c = tid & 1;
            float s = fc2b[c];
            #pragma unroll
            for (int j = 0; j < 8; ++j) s += fc2w[c * 8 + j] * shh[bl][j];
            const float sig = (s >= 0.0f) ? (1.0f / (1.0f + expf(-s)))
                                          : (expf(s) / (1.0f + expf(s)));
            const float wgt = 5.0f * sig;
            wt_ws[(b0 + bl) * 2 + c] = wgt;
            out[POOLED_SIZE + (b0 + bl) * 2 + c] = wgt;
        }
        __syncthreads();
    }
}

// -------------------------------------------------------------------------
// Clamp-coordinate sampling (equivalent to corner-clamp border mode).
// -------------------------------------------------------------------------
__device__ __forceinline__ void sample_coords(
    float gxn, float gyn, int& x0, int& y0, float& wx, float& wy)
{
    float ix = ((gxn + 1.0f) * (float)IMG - 1.0f) * 0.5f;
    float iy = ((gyn + 1.0f) * (float)IMG - 1.0f) * 0.5f;
    ix = fminf(fmaxf(ix, 0.0f), (float)(IMG - 1));
    iy = fminf(fmaxf(iy, 0.0f), (float)(IMG - 1));
    x0 = (int)ix; if (x0 > IMG - 2) x0 = IMG - 2;
    y0 = (int)iy; if (y0 > IMG - 2) y0 = IMG - 2;
    wx = ix - (float)x0;
    wy = iy - (float)y0;
}

// -------------------------------------------------------------------------
// K3 (f16 NHWC4): log-polar grid sample + 10x10 avg pool.
// Merged taps: px (x0,x0+1) contiguous 16B -> one uint4 per row per tap.
// XCD-affinity: b = (L&7) + 8*(q>>5) -> image b on XCD b%8, matching k1.
// -------------------------------------------------------------------------
__global__ __launch_bounds__(640) void k3_sample_pool_f16(
    const u16* __restrict__ x4h,      // (B,224,224,4) f16
    const float* __restrict__ ltp,
    const float* __restrict__ wt,
    float* __restrict__ out)
{
    __shared__ float part[3 * Wg];

    const int L = blockIdx.x;         // 0..2047
    const int q = L >> 3;             // 0..255
    const int h = q & 31;
    const int b = (L & 7) + 8 * (q >> 5);
    const int tid = threadIdx.x;

    const float w0 = wt[b * 2 + 0];
    const float w1 = wt[b * 2 + 1];
    const float l0 = ltp[b * 2 + 0];
    const float l1 = ltp[b * 2 + 1];
    const float start = logf(0.01f * w0);
    const float stop  = logf(0.6f  * w1);
    const float dr = stop - start;

    const float angle = 6.283185307179586f * (float)tid / (float)Wg;
    const float sn = __sinf(angle);
    const float cs = __cosf(angle);

    const u16* xb4 = x4h + (size_t)b * PLANE * 4;

    const float ratio = expf(dr * (1.0f / (float)(Hg - 1)));
    float r = expf(start + dr * ((float)(h * UPR) / (float)(Hg - 1)));

    float acc0 = 0.0f, acc1 = 0.0f, acc2 = 0.0f;
    #pragma unroll
    for (int i = 0; i < UPR; ++i) {
        int x0, y0; float wx, wy;
        sample_coords(r * sn + l0, r * cs + l1, x0, y0, wx, wy);
        r *= ratio;

        const u16* base = xb4 + ((size_t)(y0 * IMG + x0)) * 4;
        const uint4 R0 = *(const uint4*)(base);            // px x0|x0+1, row y0
        const uint4 R1 = *(const uint4*)(base + IMG * 4);  // row y0+1

        const float wx0 = 1.0f - wx, wy0 = 1.0f - wy;
        const float w00 = wx0 * wy0, w01 = wx * wy0;
        const float w10 = wx0 * wy,  w11 = wx * wy;

        acc0 += w00*h2lo(R0.x) + w01*h2lo(R0.z) + w10*h2lo(R1.x) + w11*h2lo(R1.z);
        acc1 += w00*h2hi(R0.x) + w01*h2hi(R0.z) + w10*h2hi(R1.x) + w11*h2hi(R1.z);
        acc2 += w00*h2lo(R0.y) + w01*h2lo(R0.w) + w10*h2lo(R1.y) + w11*h2lo(R1.w);
    }
    part[0 * Wg + tid] = acc0;
    part[1 * Wg + tid] = acc1;
    part[2 * Wg + tid] = acc2;
    __syncthreads();

    if (tid < Cn * Ww) {
        const int c = tid / Ww;
        const int w = tid % Ww;
        const float* p = part + c * Wg + w * UPT;
        float s = 0.0f;
        #pragma unroll
        for (int j = 0; j < UPT; ++j) s += p[j];
        out[(((size_t)b * Cn + c) * Hh + h) * Ww + w] = s * (1.0f / (UPR * UPT));
    }
}

// -------------------------------------------------------------------------
// K3 fallback (NCHW fp32 scalar gathers) — only if ws too small for x4h.
// -------------------------------------------------------------------------
__global__ __launch_bounds__(640) void k3_sample_pool_nchw(
    const float* __restrict__ x, const float* __restrict__ ltp,
    const float* __restrict__ wt, float* __restrict__ out)
{
    __shared__ float part[3 * Wg];
    const int L = blockIdx.x;
    const int q = L >> 3;
    const int h = q & 31;
    const int b = (L & 7) + 8 * (q >> 5);
    const int tid = threadIdx.x;

    const float w0 = wt[b * 2 + 0];
    const float w1 = wt[b * 2 + 1];
    const float l0 = ltp[b * 2 + 0];
    const float l1 = ltp[b * 2 + 1];
    const float start = logf(0.01f * w0);
    const float stop  = logf(0.6f  * w1);
    const float dr = stop - start;
    const float angle = 6.283185307179586f * (float)tid / (float)Wg;
    const float sn = __sinf(angle);
    const float cs = __cosf(angle);
    const float* xb = x + (size_t)b * Cn * PLANE;

    const float ratio = expf(dr * (1.0f / (float)(Hg - 1)));
    float r = expf(start + dr * ((float)(h * UPR) / (float)(Hg - 1)));

    float acc0 = 0.0f, acc1 = 0.0f, acc2 = 0.0f;
    #pragma unroll
    for (int i = 0; i < UPR; ++i) {
        int x0, y0; float wx, wy;
        sample_coords(r * sn + l0, r * cs + l1, x0, y0, wx, wy);
        r *= ratio;
        const float wx0 = 1.0f - wx, wy0 = 1.0f - wy;
        const float w00 = wx0 * wy0, w01 = wx * wy0;
        const float w10 = wx0 * wy,  w11 = wx * wy;
        const int o00 = y0 * IMG + x0;
        acc0 += w00*xb[o00] + w01*xb[o00+1] + w10*xb[o00+IMG] + w11*xb[o00+IMG+1];
        const float* x1p = xb + PLANE;
        acc1 += w00*x1p[o00] + w01*x1p[o00+1] + w10*x1p[o00+IMG] + w11*x1p[o00+IMG+1];
        const float* x2p = xb + 2 * PLANE;
        acc2 += w00*x2p[o00] + w01*x2p[o00+1] + w10*x2p[o00+IMG] + w11*x2p[o00+IMG+1];
    }
    part[0 * Wg + tid] = acc0;
    part[1 * Wg + tid] = acc1;
    part[2 * Wg + tid] = acc2;
    __syncthreads();

    if (tid < Cn * Ww) {
        const int c = tid / Ww;
        const int w = tid % Ww;
        const float* p = part + c * Wg + w * UPT;
        float s = 0.0f;
        #pragma unroll
        for (int j = 0; j < UPT; ++j) s += p[j];
        out[(((size_t)b * Cn + c) * Hh + h) * Ww + w] = s * (1.0f / (UPR * UPT));
    }
}

// -------------------------------------------------------------------------
extern "C" void kernel_launch(void* const* d_in, const int* in_sizes, int n_in,
                              void* d_out, int out_size, void* d_ws, size_t ws_size,
                              hipStream_t stream) {
    const float* x       = (const float*)d_in[0];
    const float* ltp     = (const float*)d_in[1];
    const float* conv1_w = (const float*)d_in[2];
    const float* conv1_b = (const float*)d_in[3];
    const float* conv2_w = (const float*)d_in[4];
    const float* conv2_b = (const float*)d_in[5];
    const float* fc1_w   = (const float*)d_in[6];
    const float* fc1_b   = (const float*)d_in[7];
    const float* fc2_w   = (const float*)d_in[8];
    const float* fc2_b   = (const float*)d_in[9];
    float* out = (float*)d_out;

    const int do_pack = (ws_size >= WS_NEEDED) ? 1 : 0;

    float*    wsum    = (float*)d_ws;                  // 64*152
    unsigned* counter = (unsigned*)(wsum + CTR_OFF);
    float*    wt_ws   = wsum + WT_OFF;                 // 64*2
    u16*      x4h     = (u16*)(wsum + X4H_OFF_F);      // 16B-aligned

    hipMemsetAsync(wsum, 0, MEMSET_BYTES, stream);     // wsum + counter

    k1_fused<<<dim3(NBLK1), dim3(TPB1), 0, stream>>>(
        x, conv1_w, conv1_b, conv2_w, conv2_b,
        fc1_w, fc1_b, fc2_w, fc2_b,
        wsum, counter, wt_ws, x4h, out, do_pack);

    if (do_pack)
        k3_sample_pool_f16<<<dim3(Hh * Bn), dim3(Wg), 0, stream>>>(x4h, ltp, wt_ws, out);
    else
        k3_sample_pool_nchw<<<dim3(Hh * Bn), dim3(Wg), 0, stream>>>(x, ltp, wt_ws, out);
}

// Round 5
// 173.298 us; speedup vs baseline: 2.1675x; 2.1675x over previous
//
#include <hip/hip_runtime.h>
#include <math.h>

// Problem constants
#define Bn    64
#define Cn    3
#define IMG   224
#define PLANE (IMG*IMG)      // 50176
#define C1    6
#define P1    110            // conv1(220) + maxpool2 -> 110
#define NVALID (106*106)     // 11236
#define Hh    32
#define Ww    64
#define UPR   10
#define UPT   10
#define Hg    (Hh*UPR)       // 320
#define Wg    (Ww*UPT)       // 640
#define POOLED_SIZE (Bn*Cn*Hh*Ww)   // 393216
#define NCHUNK 28            // 28 chunks x 4 pooled rows = 112 >= 110
#define PSTRIDE 152          // padded 150-float partial slot
#define ROWB  (IMG*8)        // 1792 B: one NHWC4-f16 input row
#define TPB1  448            // 7 waves: 14 strips / 7 = 2 each

typedef unsigned short u16;
typedef unsigned long long ull;
typedef _Float16 h8v __attribute__((ext_vector_type(8)));   // 8 f16 MFMA frag
typedef float f4v __attribute__((ext_vector_type(4)));      // 16x16 MFMA acc

// workspace: partials (B*28*152 f32) | wt (B*2 f32) | x4h (B*224*224*4 f16)
#define PART_FLOATS ((size_t)Bn * NCHUNK * PSTRIDE)     // 272,384
#define X4B_U16     ((size_t)Bn * PLANE * 4)
#define WS_NEEDED   ((PART_FLOATS + Bn * 2) * 4 + X4B_U16 * 2)

__device__ __forceinline__ unsigned hpack(float a, float b) {
    union { _Float16 h; u16 u; } x, y;
    x.h = (_Float16)a; y.h = (_Float16)b;
    return (unsigned)x.u | ((unsigned)y.u << 16);
}
__device__ __forceinline__ float h2lo(unsigned v) {
    union { _Float16 h; u16 u; } c; c.u = (u16)(v & 0xffffu); return (float)c.h;
}
__device__ __forceinline__ float h2hi(unsigned v) {
    union { _Float16 h; u16 u; } c; c.u = (u16)(v >> 16); return (float)c.h;
}

// group-local broadcast: read lane (group_base + idx) of a 16-lane group
#define GSHFL(v, idx) __shfl((v), (lane & 48) + (idx), 64)

// -------------------------------------------------------------------------
// K1 (MFMA f16, R2 structure — best measured 57.6us): fused conv1 +
// maxpool2 + f16-NHWC4 pack + windowed row sums -> per-chunk partials.
// Grid dim3(Bn, NCHUNK): blockIdx.x = b -> linear id % 8 = b % 8, so image
// b is served by XCD b%8 for ALL its chunks (R3 measured FETCH 28->19 MB)
// and k1's x4h writes land in the exact L2 slice k3 gathers from.
// NO device fences / atomics (R4's threadfence-per-block cost 4x).
// -------------------------------------------------------------------------
__global__ __launch_bounds__(TPB1) void k1_fused(
    const float* __restrict__ x,      // (B,3,224,224)
    const float* __restrict__ w1,     // (6,3,5,5)
    const float* __restrict__ b1,     // (6,)
    float* __restrict__ partial,      // (B,28,PSTRIDE)
    u16* __restrict__ x4h,            // (B,224,224,4) f16 out
    int do_pack)
{
    __shared__ __attribute__((aligned(16))) unsigned char xs[12 * ROWB + 128];
    __shared__ __attribute__((aligned(16))) _Float16 sa[5][64][8];  // A-frags
    __shared__ float rowR[7][C1][4];
    __shared__ float edgeLo[4][C1][4];
    __shared__ float edgeHi[4][C1][4];

    const int b     = blockIdx.x;          // XCD = b%8 (round-robin dispatch)
    const int chunk = blockIdx.y;
    const int tid   = threadIdx.x;
    const int wid   = tid >> 6;
    const int lane  = tid & 63;
    const int n     = lane & 15;           // B col / A row / C col
    const int g     = lane >> 4;           // K-group (and C row-group)
    const int gy0   = chunk * 8;

    const float* xb = x + (size_t)b * (Cn * PLANE);
    u16* ob = x4h + (size_t)b * PLANE * 4;

    if (wid == 0) {
        // wave 0: build A-frags (weights, k = ic + 4*kx) into LDS
        #pragma unroll
        for (int ky = 0; ky < 5; ++ky) {
            #pragma unroll
            for (int j = 0; j < 8; ++j) {
                const int kmem = g * 8 + j;
                const int ic = kmem & 3, kx = kmem >> 2;
                float w = 0.0f;
                if (n < C1 && ic < 3 && kx < 5)
                    w = w1[((n * 3 + ic) * 5 + ky) * 5 + kx];
                sa[ky][lane][j] = (_Float16)w;
            }
        }
    } else {
        // waves 1-6: stage fp32 NCHW -> f16 NHWC4 LDS (+ x4h pack)
        for (int i = tid - 64; i < 12 * 112; i += TPB1 - 64) {
            const int r = i / 112;
            const int p = i - r * 112;
            const int gy = gy0 + r;
            uint4 U; U.x = U.y = U.z = U.w = 0u;
            if (gy < IMG) {
                const float2 v0 = *(const float2*)(xb + 0 * PLANE + gy * IMG + 2 * p);
                const float2 v1 = *(const float2*)(xb + 1 * PLANE + gy * IMG + 2 * p);
                const float2 v2 = *(const float2*)(xb + 2 * PLANE + gy * IMG + 2 * p);
                U.x = hpack(v0.x, v1.x);
                U.y = hpack(v2.x, 0.0f);
                U.z = hpack(v0.y, v1.y);
                U.w = hpack(v2.y, 0.0f);
            }
            *(uint4*)(xs + r * ROWB + p * 16) = U;
            if (do_pack && r < 8)
                *(uint4*)(ob + ((size_t)gy * IMG + 2 * p) * 4) = U;
        }
    }
    __syncthreads();

    // per-lane A-frags (one b128 each) + bias init
    h8v a[5];
    #pragma unroll
    for (int ky = 0; ky < 5; ++ky) a[ky] = *(const h8v*)&sa[ky][lane][0];
    f4v binit;
    #pragma unroll
    for (int e = 0; e < 4; ++e) {
        const int oc = g * 4 + e;
        binit[e] = (oc < C1) ? b1[oc] : 0.0f;
    }

    float colsum[4][4];
    #pragma unroll
    for (int py = 0; py < 4; ++py)
        #pragma unroll
        for (int e = 0; e < 4; ++e) colsum[py][e] = 0.0f;

    #pragma unroll
    for (int si = 0; si < 2; ++si) {
        const int s = wid * 2 + si;         // strip: conv cols s*16..s*16+15
        const unsigned sByte = (unsigned)(s * 128 + n * 8 + g * 16);

        f4v acc[8];
        #pragma unroll
        for (int q = 0; q < 8; ++q) acc[q] = binit;

        #pragma unroll
        for (int r = 0; r < 12; ++r) {
            h8v bf;
            const unsigned char* bp = xs + r * ROWB + sByte;
            ((ull*)&bf)[0] = *(const ull*)bp;
            ((ull*)&bf)[1] = *(const ull*)(bp + 8);
            #pragma unroll
            for (int ky = 0; ky < 5; ++ky) {
                const int q = r - ky;
                if (q >= 0 && q < 8)
                    acc[q] = __builtin_amdgcn_mfma_f32_16x16x32_f16(
                        a[ky], bf, acc[q], 0, 0, 0);
            }
        }

        // maxpool 2x2 + edge capture + col accumulation
        #pragma unroll
        for (int py = 0; py < 4; ++py) {
            #pragma unroll
            for (int e = 0; e < 4; ++e) {
                float t = fmaxf(acc[2 * py][e], acc[2 * py + 1][e]);
                t = fmaxf(t, __shfl_xor(t, 1, 64));
                if (s == 13 && n >= 12) t = 0.0f;     // junk cols 110,111
                colsum[py][e] += t;
                const int oc = g * 4 + e;
                if (s == 0) {                          // pooled cols 0..3
                    const float c0 = GSHFL(t, 0), c1 = GSHFL(t, 2);
                    const float c2 = GSHFL(t, 4), c3 = GSHFL(t, 6);
                    const float S1 = c0, S2 = S1 + c1, S3 = S2 + c2, S4 = S3 + c3;
                    const float sv = (n == 0) ? S1 : (n == 1) ? S2 : (n == 2) ? S3 : S4;
                    if (n < 4 && oc < C1) edgeLo[py][oc][n] = sv;
                }
                if (s == 13) {                         // pooled cols 106..109
                    const float d109 = GSHFL(t, 10), d108 = GSHFL(t, 8);
                    const float d107 = GSHFL(t, 6),  d106 = GSHFL(t, 4);
                    const float U1 = d109, U2 = U1 + d108, U3 = U2 + d107, U4 = U3 + d106;
                    const float uv = (n == 0) ? U1 : (n == 1) ? U2 : (n == 2) ? U3 : U4;
                    if (n < 4 && oc < C1) edgeHi[py][oc][n] = uv;
                }
            }
        }
    }

    // per-wave row sums
    #pragma unroll
    for (int py = 0; py < 4; ++py) {
        #pragma unroll
        for (int e = 0; e < 4; ++e) {
            float v = colsum[py][e];
            v += __shfl_xor(v, 2, 64);
            v += __shfl_xor(v, 4, 64);
            v += __shfl_xor(v, 8, 64);
            const int oc = g * 4 + e;
            if (n == 0 && oc < C1) rowR[wid][oc][py] = v;
        }
    }
    __syncthreads();

    // final: slot(oc,ky,kx) = sum_py valid(py,ky) * (rowsum - S_kx - U_{4-kx})
    if (tid < 150) {
        const int oc = tid / 25;
        const int rem = tid - oc * 25;
        const int ky = rem / 5, kx = rem - ky * 5;
        float total = 0.0f;
        #pragma unroll
        for (int py = 0; py < 4; ++py) {
            const int y = chunk * 4 + py;
            const bool valid = (y < P1) && ((unsigned)(y - ky) <= 105u);
            float v = rowR[0][oc][py] + rowR[1][oc][py] + rowR[2][oc][py]
                    + rowR[3][oc][py] + rowR[4][oc][py] + rowR[5][oc][py]
                    + rowR[6][oc][py];
            if (kx > 0) v -= edgeLo[py][oc][kx - 1];
            if (kx < 4) v -= edgeHi[py][oc][3 - kx];
            total += valid ? v : 0.0f;
        }
        partial[((size_t)b * NCHUNK + chunk) * PSTRIDE + tid] = total;
    }
}

// -------------------------------------------------------------------------
// K2: reduce partials -> wsum_b; feat; fc1+relu; fc2+sigmoid*5.
// One block (256 threads) per batch element. ~4us.
// -------------------------------------------------------------------------
__global__ __launch_bounds__(256) void k2_head(
    const float* __restrict__ partial, const float* __restrict__ w2,
    const float* __restrict__ b2, const float* __restrict__ fc1w,
    const float* __restrict__ fc1b, const float* __restrict__ fc2w,
    const float* __restrict__ fc2b, float* __restrict__ wt_ws,
    float* __restrict__ out)
{
    const int b = blockIdx.x;
    const int tid = threadIdx.x;
    __shared__ float wsb[150];
    __shared__ float sfeat[16];
    __shared__ float sh[8];

    if (tid < 150) {
        const float* p = partial + (size_t)b * NCHUNK * PSTRIDE + tid;
        float s = 0.0f;
        #pragma unroll
        for (int c = 0; c < NCHUNK; ++c) s += p[c * PSTRIDE];
        wsb[tid] = s;
    }
    __syncthreads();
    if (tid < 16) {
        float s = 0.0f;
        for (int j = 0; j < 150; ++j) s += w2[tid * 150 + j] * wsb[j];
        sfeat[tid] = b2[tid] + s * (1.0f / (float)NVALID);
    }
    __syncthreads();
    if (tid < 8) {
        float s = fc1b[tid];
        #pragma unroll
        for (int j = 0; j < 16; ++j) s += fc1w[tid * 16 + j] * sfeat[j];
        sh[tid] = fmaxf(s, 0.0f);
    }
    __syncthreads();
    if (tid < 2) {
        float s = fc2b[tid];
        #pragma unroll
        for (int j = 0; j < 8; ++j) s += fc2w[tid * 8 + j] * sh[j];
        float sig = (s >= 0.0f) ? (1.0f / (1.0f + expf(-s)))
                                : (expf(s) / (1.0f + expf(s)));
        const float wgt = 5.0f * sig;
        wt_ws[b * 2 + tid] = wgt;
        out[POOLED_SIZE + b * 2 + tid] = wgt;
    }
}

// -------------------------------------------------------------------------
// Clamp-coordinate sampling (equivalent to corner-clamp border mode).
// -------------------------------------------------------------------------
__device__ __forceinline__ void sample_coords(
    float gxn, float gyn, int& x0, int& y0, float& wx, float& wy)
{
    float ix = ((gxn + 1.0f) * (float)IMG - 1.0f) * 0.5f;
    float iy = ((gyn + 1.0f) * (float)IMG - 1.0f) * 0.5f;
    ix = fminf(fmaxf(ix, 0.0f), (float)(IMG - 1));
    iy = fminf(fmaxf(iy, 0.0f), (float)(IMG - 1));
    x0 = (int)ix; if (x0 > IMG - 2) x0 = IMG - 2;
    y0 = (int)iy; if (y0 > IMG - 2) y0 = IMG - 2;
    wx = ix - (float)x0;
    wy = iy - (float)y0;
}

// -------------------------------------------------------------------------
// K3 (f16 NHWC4, chain-broken): log-polar grid sample + 10x10 avg pool.
// ROUND-5 KEY CHANGE: radii computed with 10 INDEPENDENT __expf calls
// (was r *= ratio serial chain -> each gather address depended on the
// previous sample's, so only ~2 loads in flight). Now all 10 coords are
// computed up-front and gathers issue in 5-sample batches (10 outstanding
// loads/thread) — attacks the gather-LATENCY bound that the R0->R1
// tap-count halving (no effect) diagnosed.
// XCD-affinity: b = (L&7) + 8*(q>>5) -> image b on XCD b%8, matching k1.
// -------------------------------------------------------------------------
__global__ __launch_bounds__(640) void k3_sample_pool_f16(
    const u16* __restrict__ x4h,      // (B,224,224,4) f16
    const float* __restrict__ ltp,
    const float* __restrict__ wt,
    float* __restrict__ out)
{
    __shared__ float part[3 * Wg];

    const int L = blockIdx.x;         // 0..2047
    const int q = L >> 3;             // 0..255
    const int h = q & 31;
    const int b = (L & 7) + 8 * (q >> 5);
    const int tid = threadIdx.x;

    const float w0 = wt[b * 2 + 0];
    const float w1 = wt[b * 2 + 1];
    const float l0 = ltp[b * 2 + 0];
    const float l1 = ltp[b * 2 + 1];
    const float start = logf(0.01f * w0);
    const float stop  = logf(0.6f  * w1);
    const float dr = stop - start;

    const float angle = 6.283185307179586f * (float)tid / (float)Wg;
    const float sn = __sinf(angle);
    const float cs = __cosf(angle);

    const u16* xb4 = x4h + (size_t)b * PLANE * 4;

    // all 10 sample coords up-front (independent exps, no serial chain)
    int xi[UPR], yi[UPR];
    float wxa[UPR], wya[UPR];
    #pragma unroll
    for (int i = 0; i < UPR; ++i) {
        const float ri = __expf(start + dr * ((float)(h * UPR + i)
                                              * (1.0f / (float)(Hg - 1))));
        sample_coords(ri * sn + l0, ri * cs + l1, xi[i], yi[i], wxa[i], wya[i]);
    }

    float acc0 = 0.0f, acc1 = 0.0f, acc2 = 0.0f;
    #pragma unroll
    for (int bb = 0; bb < 2; ++bb) {
        uint4 R0[5], R1[5];
        #pragma unroll
        for (int i = 0; i < 5; ++i) {           // issue 10 gathers together
            const int s = bb * 5 + i;
            const u16* base = xb4 + ((size_t)(yi[s] * IMG + xi[s])) * 4;
            R0[i] = *(const uint4*)(base);            // px x0|x0+1, row y0
            R1[i] = *(const uint4*)(base + IMG * 4);  // row y0+1
        }
        #pragma unroll
        for (int i = 0; i < 5; ++i) {
            const int s = bb * 5 + i;
            const float wx = wxa[s], wy = wya[s];
            const float wx0 = 1.0f - wx, wy0 = 1.0f - wy;
            const float w00 = wx0 * wy0, w01 = wx * wy0;
            const float w10 = wx0 * wy,  w11 = wx * wy;
            acc0 += w00*h2lo(R0[i].x) + w01*h2lo(R0[i].z)
                  + w10*h2lo(R1[i].x) + w11*h2lo(R1[i].z);
            acc1 += w00*h2hi(R0[i].x) + w01*h2hi(R0[i].z)
                  + w10*h2hi(R1[i].x) + w11*h2hi(R1[i].z);
            acc2 += w00*h2lo(R0[i].y) + w01*h2lo(R0[i].w)
                  + w10*h2lo(R1[i].y) + w11*h2lo(R1[i].w);
        }
    }
    part[0 * Wg + tid] = acc0;
    part[1 * Wg + tid] = acc1;
    part[2 * Wg + tid] = acc2;
    __syncthreads();

    if (tid < Cn * Ww) {
        const int c = tid / Ww;
        const int w = tid % Ww;
        const float* p = part + c * Wg + w * UPT;
        float s = 0.0f;
        #pragma unroll
        for (int j = 0; j < UPT; ++j) s += p[j];
        out[(((size_t)b * Cn + c) * Hh + h) * Ww + w] = s * (1.0f / (UPR * UPT));
    }
}

// -------------------------------------------------------------------------
// K3 fallback (NCHW fp32 scalar gathers) — only if ws too small for x4h.
// -------------------------------------------------------------------------
__global__ __launch_bounds__(640) void k3_sample_pool_nchw(
    const float* __restrict__ x, const float* __restrict__ ltp,
    const float* __restrict__ wt, float* __restrict__ out)
{
    __shared__ float part[3 * Wg];
    const int L = blockIdx.x;
    const int q = L >> 3;
    const int h = q & 31;
    const int b = (L & 7) + 8 * (q >> 5);
    const int tid = threadIdx.x;

    const float w0 = wt[b * 2 + 0];
    const float w1 = wt[b * 2 + 1];
    const float l0 = ltp[b * 2 + 0];
    const float l1 = ltp[b * 2 + 1];
    const float start = logf(0.01f * w0);
    const float stop  = logf(0.6f  * w1);
    const float dr = stop - start;
    const float angle = 6.283185307179586f * (float)tid / (float)Wg;
    const float sn = __sinf(angle);
    const float cs = __cosf(angle);
    const float* xb = x + (size_t)b * Cn * PLANE;

    float acc0 = 0.0f, acc1 = 0.0f, acc2 = 0.0f;
    #pragma unroll
    for (int i = 0; i < UPR; ++i) {
        const float ri = __expf(start + dr * ((float)(h * UPR + i)
                                              * (1.0f / (float)(Hg - 1))));
        int x0, y0; float wx, wy;
        sample_coords(ri * sn + l0, ri * cs + l1, x0, y0, wx, wy);
        const float wx0 = 1.0f - wx, wy0 = 1.0f - wy;
        const float w00 = wx0 * wy0, w01 = wx * wy0;
        const float w10 = wx0 * wy,  w11 = wx * wy;
        const int o00 = y0 * IMG + x0;
        acc0 += w00*xb[o00] + w01*xb[o00+1] + w10*xb[o00+IMG] + w11*xb[o00+IMG+1];
        const float* x1p = xb + PLANE;
        acc1 += w00*x1p[o00] + w01*x1p[o00+1] + w10*x1p[o00+IMG] + w11*x1p[o00+IMG+1];
        const float* x2p = xb + 2 * PLANE;
        acc2 += w00*x2p[o00] + w01*x2p[o00+1] + w10*x2p[o00+IMG] + w11*x2p[o00+IMG+1];
    }
    part[0 * Wg + tid] = acc0;
    part[1 * Wg + tid] = acc1;
    part[2 * Wg + tid] = acc2;
    __syncthreads();

    if (tid < Cn * Ww) {
        const int c = tid / Ww;
        const int w = tid % Ww;
        const float* p = part + c * Wg + w * UPT;
        float s = 0.0f;
        #pragma unroll
        for (int j = 0; j < UPT; ++j) s += p[j];
        out[(((size_t)b * Cn + c) * Hh + h) * Ww + w] = s * (1.0f / (UPR * UPT));
    }
}

// -------------------------------------------------------------------------
extern "C" void kernel_launch(void* const* d_in, const int* in_sizes, int n_in,
                              void* d_out, int out_size, void* d_ws, size_t ws_size,
                              hipStream_t stream) {
    const float* x       = (const float*)d_in[0];
    const float* ltp     = (const float*)d_in[1];
    const float* conv1_w = (const float*)d_in[2];
    const float* conv1_b = (const float*)d_in[3];
    const float* conv2_w = (const float*)d_in[4];
    const float* conv2_b = (const float*)d_in[5];
    const float* fc1_w   = (const float*)d_in[6];
    const float* fc1_b   = (const float*)d_in[7];
    const float* fc2_w   = (const float*)d_in[8];
    const float* fc2_b   = (const float*)d_in[9];
    float* out = (float*)d_out;

    const int do_pack = (ws_size >= WS_NEEDED) ? 1 : 0;

    float* part_ws = (float*)d_ws;                // B*28*PSTRIDE
    float* wt_ws   = part_ws + PART_FLOATS;       // B*2
    u16*   x4h     = (u16*)(wt_ws + Bn * 2);      // 8B-aligned

    k1_fused<<<dim3(Bn, NCHUNK), dim3(TPB1), 0, stream>>>(
        x, conv1_w, conv1_b, part_ws, x4h, do_pack);
    k2_head<<<dim3(Bn), dim3(256), 0, stream>>>(part_ws, conv2_w, conv2_b,
                                                fc1_w, fc1_b, fc2_w, fc2_b,
                                                wt_ws, out);
    if (do_pack)
        k3_sample_pool_f16<<<dim3(Hh * Bn), dim3(Wg), 0, stream>>>(x4h, ltp, wt_ws, out);
    else
        k3_sample_pool_nchw<<<dim3(Hh * Bn), dim3(Wg), 0, stream>>>(x, ltp, wt_ws, out);
}